// Round 3
// baseline (1953.854 us; speedup 1.0000x reference)
//
#include <hip/hip_runtime.h>
#include <hip/hip_bf16.h>

#define N_PTS 400000
#define KOFF 27

typedef __attribute__((ext_vector_type(8))) short short8;
typedef __attribute__((ext_vector_type(4))) float float4v;

__device__ __forceinline__ unsigned short f2bf(float f) {
    union { float f; unsigned int u; } a; a.f = f;
    unsigned int u = a.u;
    unsigned int r = (u + 0x7FFFu + ((u >> 16) & 1u)) >> 16;
    return (unsigned short)r;
}

__device__ __forceinline__ float bf2f(unsigned short u) {
    union { unsigned int u; float f; } a; a.u = ((unsigned int)u) << 16;
    return a.f;
}

// ---- cast features fp32 -> bf16 ----
__global__ void cast_feat_kernel(const float* __restrict__ src,
                                 unsigned short* __restrict__ dst, int n4) {
    int i = blockIdx.x * blockDim.x + threadIdx.x;
    if (i >= n4) return;
    const float4* s4 = (const float4*)src;
    float4 v = s4[i];
    ushort4 o;
    o.x = f2bf(v.x); o.y = f2bf(v.y); o.z = f2bf(v.z); o.w = f2bf(v.w);
    ((ushort4*)dst)[i] = o;
}

// ---- one-shot prep: transpose+cast all 3 weight sets, zero all stats ----
__global__ void prep_w_all_kernel(const float* __restrict__ W1,
                                  const float* __restrict__ W2,
                                  const float* __restrict__ W3,
                                  unsigned short* __restrict__ Wt,
                                  float* __restrict__ stats) {
    int i = blockIdx.x * blockDim.x + threadIdx.x;
    if (i < 384) stats[i] = 0.0f;
    if (i >= KOFF * 64 * 64) return;
    int k = i >> 12;
    int co = (i >> 6) & 63;
    int ci = i & 63;
    int src = (k << 12) + (ci << 6) + co;
    const int WS = KOFF * 4096;
    Wt[i] = f2bf(W1[src]);
    Wt[i + WS] = f2bf(W2[src]);
    Wt[i + 2 * WS] = f2bf(W3[src]);
}

// ---- gather-GEMM + fused BN-stats reduction, BARRIER-FREE main loop ----
// X: [N][64] bf16, nbr: [N][27] int, Wt: [27][64(co)][64(ci)] bf16
// Y: [N][64] fp32, stats: [128] fp32 (sum, sumsq) pre-zeroed
// Block: 256 threads = 4 waves; each wave owns 32 rows (two 16-row MFMA
// tiles sharing B fragments). A-fragments are gathered DIRECT to registers
// (per-lane 16B loads match the MFMA A layout: row=l16, kchunk=quad*8),
// so no LDS staging and no __syncthreads in the k-loop -> gather loads
// stay in flight across iterations with counted vmcnt (no barrier drain).
// Depth-2 pipeline: consume k, refill k+2, index prefetch k+3.
__global__ __launch_bounds__(256, 4)
void conv_kernel(const unsigned short* __restrict__ X,
                 const int* __restrict__ nbr,
                 const unsigned short* __restrict__ Wt,
                 float* __restrict__ Y,
                 float* __restrict__ stats) {
    __shared__ float red[128];
    const int tid = threadIdx.x;
    const int wave = tid >> 6;
    const int lane = tid & 63;
    const int quad = lane >> 4;
    const int l16 = lane & 15;
    const int p0 = blockIdx.x * 128;
    const int r0 = p0 + wave * 32 + l16;   // half-0 row for this lane
    const int r1 = r0 + 16;                // half-1 row

    const int* nb0 = nbr + (size_t)r0 * KOFF;
    const int* nb1 = nbr + (size_t)r1 * KOFF;
    const unsigned short* Xq = X + quad * 8;  // lane's 16B chunk base

    float4v acc[2][4];
    #pragma unroll
    for (int h = 0; h < 2; ++h)
        #pragma unroll
        for (int t = 0; t < 4; ++t) acc[h][t] = (float4v){0.f, 0.f, 0.f, 0.f};

    // ---- prologue: fill depth-2 pipeline ----
    short8 a00, a01, a10, a11;   // set A: data for k   (half0 ks0/ks1, half1 ks0/ks1)
    short8 b00, b01, b10, b11;   // set B: data for k+1
    {
        const unsigned short* s0 = Xq + ((size_t)nb0[0] << 6);
        const unsigned short* s1 = Xq + ((size_t)nb1[0] << 6);
        a00 = *(const short8*)s0; a01 = *(const short8*)(s0 + 32);
        a10 = *(const short8*)s1; a11 = *(const short8*)(s1 + 32);
    }
    {
        const unsigned short* s0 = Xq + ((size_t)nb0[1] << 6);
        const unsigned short* s1 = Xq + ((size_t)nb1[1] << 6);
        b00 = *(const short8*)s0; b01 = *(const short8*)(s0 + 32);
        b10 = *(const short8*)s1; b11 = *(const short8*)(s1 + 32);
    }
    int ic0 = nb0[2], ic1 = nb1[2];   // indices for k+2

    for (int k = 0; k < KOFF; ++k) {
        // prefetch indices for k+3 (1 full iteration of lead time)
        int jn0 = 0, jn1 = 0;
        if (k + 3 < KOFF) { jn0 = nb0[k + 3]; jn1 = nb1[k + 3]; }

        // B fragments for this k: coalesced 16B/lane from L1/L2-resident Wt
        const unsigned short* wk = Wt + ((size_t)k << 12) + l16 * 64 + quad * 8;
        #pragma unroll
        for (int ks = 0; ks < 2; ++ks) {
            #pragma unroll
            for (int t = 0; t < 4; ++t) {
                short8 bf = *(const short8*)(wk + t * 1024 + ks * 32);
                acc[0][t] = __builtin_amdgcn_mfma_f32_16x16x32_bf16(
                    ks ? a01 : a00, bf, acc[0][t], 0, 0, 0);
                acc[1][t] = __builtin_amdgcn_mfma_f32_16x16x32_bf16(
                    ks ? a11 : a10, bf, acc[1][t], 0, 0, 0);
            }
        }

        // set A consumed; refill with k+2 gathers (in flight ~1.2 iters)
        if (k + 2 < KOFF) {
            const unsigned short* s0 = Xq + ((size_t)ic0 << 6);
            const unsigned short* s1 = Xq + ((size_t)ic1 << 6);
            a00 = *(const short8*)s0; a01 = *(const short8*)(s0 + 32);
            a10 = *(const short8*)s1; a11 = *(const short8*)(s1 + 32);
        }
        // rotate: next iteration consumes old set B
        short8 t0;
        t0 = a00; a00 = b00; b00 = t0;
        t0 = a01; a01 = b01; b01 = t0;
        t0 = a10; a10 = b10; b10 = t0;
        t0 = a11; a11 = b11; b11 = t0;
        ic0 = jn0; ic1 = jn1;
    }

    // write C: row = p0 + wave*32 + half*16 + quad*4 + r, col = t*16 + l16
    #pragma unroll
    for (int h = 0; h < 2; ++h) {
        const int row_base = p0 + wave * 32 + h * 16 + quad * 4;
        #pragma unroll
        for (int t = 0; t < 4; ++t) {
            #pragma unroll
            for (int r = 0; r < 4; ++r) {
                Y[(size_t)(row_base + r) * 64 + t * 16 + l16] = acc[h][t][r];
            }
        }
    }

    // fused BN stats: per-lane over 2x4 rows -> shuffle -> LDS -> 1 atomic/block
    if (tid < 128) red[tid] = 0.0f;
    __syncthreads();
    #pragma unroll
    for (int t = 0; t < 4; ++t) {
        float s = 0.f, ss = 0.f;
        #pragma unroll
        for (int h = 0; h < 2; ++h) {
            #pragma unroll
            for (int r = 0; r < 4; ++r) {
                float v = acc[h][t][r];
                s += v;
                ss += v * v;
            }
        }
        s += __shfl_down(s, 32);
        s += __shfl_down(s, 16);
        ss += __shfl_down(ss, 32);
        ss += __shfl_down(ss, 16);
        if (lane < 16) {
            atomicAdd(&red[t * 16 + l16], s);
            atomicAdd(&red[64 + t * 16 + l16], ss);
        }
    }
    __syncthreads();
    if (tid < 128) atomicAdd(&stats[tid], red[tid]);
}

// ---- bn + leakyrelu -> bf16 output (input to next conv) ----
__global__ void bnact_kernel(const float* __restrict__ Y, const float* __restrict__ stats,
                             const float* __restrict__ g, const float* __restrict__ b,
                             unsigned short* __restrict__ Xb, float slope) {
    __shared__ float scale[64], shift[64];
    int tid = threadIdx.x;
    if (tid < 64) {
        float m = stats[tid] * (1.0f / N_PTS);
        float v = stats[64 + tid] * (1.0f / N_PTS) - m * m;
        float rs = rsqrtf(v + 1e-4f);
        float sc = rs * g[tid];
        scale[tid] = sc;
        shift[tid] = b[tid] - m * sc;
    }
    __syncthreads();
    int i = blockIdx.x * blockDim.x + tid;
    const int total = N_PTS * 16;
    if (i >= total) return;
    int cb = (i & 15) << 2;
    float4 y = ((const float4*)Y)[i];
    float o0 = y.x * scale[cb] + shift[cb];
    float o1 = y.y * scale[cb + 1] + shift[cb + 1];
    float o2 = y.z * scale[cb + 2] + shift[cb + 2];
    float o3 = y.w * scale[cb + 3] + shift[cb + 3];
    o0 = o0 >= 0.f ? o0 : slope * o0;
    o1 = o1 >= 0.f ? o1 : slope * o1;
    o2 = o2 >= 0.f ? o2 : slope * o2;
    o3 = o3 >= 0.f ? o3 : slope * o3;
    ushort4 o;
    o.x = f2bf(o0); o.y = f2bf(o1); o.z = f2bf(o2); o.w = f2bf(o3);
    ((ushort4*)Xb)[i] = o;
}

// ---- final: bn3 + residual + leakyrelu(0.333) -> fp32 d_out (in place over Y) ----
__global__ void bnact_final_kernel(float* __restrict__ Y, const float* __restrict__ stats,
                                   const float* __restrict__ g, const float* __restrict__ b,
                                   const unsigned short* __restrict__ res) {
    __shared__ float scale[64], shift[64];
    int tid = threadIdx.x;
    if (tid < 64) {
        float m = stats[tid] * (1.0f / N_PTS);
        float v = stats[64 + tid] * (1.0f / N_PTS) - m * m;
        float rs = rsqrtf(v + 1e-4f);
        float sc = rs * g[tid];
        scale[tid] = sc;
        shift[tid] = b[tid] - m * sc;
    }
    __syncthreads();
    int i = blockIdx.x * blockDim.x + tid;
    const int total = N_PTS * 16;
    if (i >= total) return;
    int cb = (i & 15) << 2;
    float4 y = ((const float4*)Y)[i];
    ushort4 r4 = ((const ushort4*)res)[i];
    float o0 = y.x * scale[cb] + shift[cb] + bf2f(r4.x);
    float o1 = y.y * scale[cb + 1] + shift[cb + 1] + bf2f(r4.y);
    float o2 = y.z * scale[cb + 2] + shift[cb + 2] + bf2f(r4.z);
    float o3 = y.w * scale[cb + 3] + shift[cb + 3] + bf2f(r4.w);
    o0 = o0 >= 0.f ? o0 : 0.333f * o0;
    o1 = o1 >= 0.f ? o1 : 0.333f * o1;
    o2 = o2 >= 0.f ? o2 : 0.333f * o2;
    o3 = o3 >= 0.f ? o3 : 0.333f * o3;
    float4 o; o.x = o0; o.y = o1; o.z = o2; o.w = o3;
    ((float4*)Y)[i] = o;
}

extern "C" void kernel_launch(void* const* d_in, const int* in_sizes, int n_in,
                              void* d_out, int out_size, void* d_ws, size_t ws_size,
                              hipStream_t stream) {
    const float* feat = (const float*)d_in[0];
    const int* nbr = (const int*)d_in[1];
    const float* W1 = (const float*)d_in[2];
    const float* g1 = (const float*)d_in[3];
    const float* b1 = (const float*)d_in[4];
    const float* W2 = (const float*)d_in[5];
    const float* g2 = (const float*)d_in[6];
    const float* b2 = (const float*)d_in[7];
    const float* W3 = (const float*)d_in[8];
    const float* g3 = (const float*)d_in[9];
    const float* b3 = (const float*)d_in[10];
    float* Y = (float*)d_out;

    char* ws = (char*)d_ws;
    const size_t BF_BYTES = (size_t)N_PTS * 64 * 2;  // 51.2 MB
    unsigned short* B0 = (unsigned short*)ws;
    unsigned short* B1 = (unsigned short*)(ws + BF_BYTES);
    unsigned short* Wt = (unsigned short*)(ws + 2 * BF_BYTES);
    float* stats = (float*)(ws + 2 * BF_BYTES + (size_t)3 * KOFF * 4096 * 2);

    const int WSTRIDE = KOFF * 4096;  // 110592

    cast_feat_kernel<<<25000, 256, 0, stream>>>(feat, B0, N_PTS * 16);
    prep_w_all_kernel<<<(KOFF * 4096 + 255) / 256, 256, 0, stream>>>(W1, W2, W3, Wt, stats);

    // block 1
    conv_kernel<<<N_PTS / 128, 256, 0, stream>>>(B0, nbr, Wt, Y, stats);
    bnact_kernel<<<25000, 256, 0, stream>>>(Y, stats, g1, b1, B1, 0.05f);
    // block 2
    conv_kernel<<<N_PTS / 128, 256, 0, stream>>>(B1, nbr, Wt + WSTRIDE, Y, stats + 128);
    bnact_kernel<<<25000, 256, 0, stream>>>(Y, stats + 128, g2, b2, B0, 0.05f);
    // block 3 + residual
    conv_kernel<<<N_PTS / 128, 256, 0, stream>>>(B0, nbr, Wt + 2 * WSTRIDE, Y, stats + 256);
    bnact_final_kernel<<<25000, 256, 0, stream>>>(Y, stats + 256, g3, b3, B1);
}

// Round 4
// 1016.878 us; speedup vs baseline: 1.9214x; 1.9214x over previous
//
#include <hip/hip_runtime.h>
#include <hip/hip_bf16.h>

#define N_PTS 400000
#define KOFF 27
#define AP 72  // LDS row pitch in ushorts: 144B, breaks pow2 bank aliasing

typedef __attribute__((ext_vector_type(8))) short short8;
typedef __attribute__((ext_vector_type(4))) float float4v;

__device__ __forceinline__ unsigned short f2bf(float f) {
    union { float f; unsigned int u; } a; a.f = f;
    unsigned int u = a.u;
    unsigned int r = (u + 0x7FFFu + ((u >> 16) & 1u)) >> 16;
    return (unsigned short)r;
}

__device__ __forceinline__ float bf2f(unsigned short u) {
    union { unsigned int u; float f; } a; a.u = ((unsigned int)u) << 16;
    return a.f;
}

// ---- cast features fp32 -> bf16 ----
__global__ void cast_feat_kernel(const float* __restrict__ src,
                                 unsigned short* __restrict__ dst, int n4) {
    int i = blockIdx.x * blockDim.x + threadIdx.x;
    if (i >= n4) return;
    const float4* s4 = (const float4*)src;
    float4 v = s4[i];
    ushort4 o;
    o.x = f2bf(v.x); o.y = f2bf(v.y); o.z = f2bf(v.z); o.w = f2bf(v.w);
    ((ushort4*)dst)[i] = o;
}

// ---- one-shot prep: transpose+cast all 3 weight sets, zero all stats ----
__global__ void prep_w_all_kernel(const float* __restrict__ W1,
                                  const float* __restrict__ W2,
                                  const float* __restrict__ W3,
                                  unsigned short* __restrict__ Wt,
                                  float* __restrict__ stats) {
    int i = blockIdx.x * blockDim.x + threadIdx.x;
    if (i < 384) stats[i] = 0.0f;
    if (i >= KOFF * 64 * 64) return;
    int k = i >> 12;
    int co = (i >> 6) & 63;
    int ci = i & 63;
    int src = (k << 12) + (ci << 6) + co;
    const int WS = KOFF * 4096;
    Wt[i] = f2bf(W1[src]);
    Wt[i + WS] = f2bf(W2[src]);
    Wt[i + 2 * WS] = f2bf(W3[src]);
}

// ---- gather-GEMM + fused BN-stats reduction ----
// X: [N][64] bf16, nbr: [N][27] int, Wt: [27][64(co)][64(ci)] bf16
// Y: [N][64] fp32, stats: [128] fp32 (sum, sumsq) pre-zeroed
// Block: 512 threads (8 waves), M-tile = 128 points; register prefetch dbuf.
// launch_bounds(512, 8): 8 waves/SIMD = 4 blocks/CU (VGPR 36 <= 64,
// LDS 4x27.6KB = 110KB <= 160KB). The 4th resident block gives the CU a
// runnable block while others sit in the per-iteration barrier drain.
__global__ __launch_bounds__(512, 8)
void conv_kernel(const unsigned short* __restrict__ X,
                 const int* __restrict__ nbr,
                 const unsigned short* __restrict__ Wt,
                 float* __restrict__ Y,
                 float* __restrict__ stats) {
    __shared__ unsigned short lds_a[128 * AP];  // 18432 B
    __shared__ unsigned short lds_w[64 * AP];   //  9216 B
    const int tid = threadIdx.x;
    const int wave = tid >> 6;
    const int lane = tid & 63;
    const int quad = lane >> 4;
    const int l16 = lane & 15;
    const int p0 = blockIdx.x * 128;

    const int sr = tid >> 2;   // staging row 0..127 (4 threads/row)
    const int sq = tid & 3;    // 32B quarter of the 128B row
    const int wr = tid >> 3;   // W staging row (512 thr x 16B covers 8KB)
    const int wc = (tid & 7) << 3;

    float4v acc[4];
    #pragma unroll
    for (int t = 0; t < 4; ++t) acc[t] = (float4v){0.f, 0.f, 0.f, 0.f};

    // prefetch pipeline: indices 2 ahead, rows/weights 1 ahead
    const long nb = (long)(p0 + sr) * KOFF;
    int gi = nbr[nb];
    int gin = nbr[nb + 1];
    uint4 a0, a1, w0;
    {
        const uint4* srcA = (const uint4*)(X + ((size_t)gi << 6)) + sq * 2;
        a0 = srcA[0];
        a1 = srcA[1];
        w0 = ((const uint4*)Wt)[tid];
    }

    for (int k = 0; k < KOFF; ++k) {
        __syncthreads();  // previous iteration's compute done reading LDS
        *(uint4*)(lds_a + sr * AP + sq * 16) = a0;
        *(uint4*)(lds_a + sr * AP + sq * 16 + 8) = a1;
        *(uint4*)(lds_w + wr * AP + wc) = w0;
        if (k < KOFF - 1) {
            const uint4* srcA = (const uint4*)(X + ((size_t)gin << 6)) + sq * 2;
            a0 = srcA[0];
            a1 = srcA[1];
            w0 = ((const uint4*)(Wt + (((size_t)(k + 1)) << 12)))[tid];
            gin = (k < KOFF - 2) ? nbr[nb + k + 2] : 0;
        }
        __syncthreads();  // staged data visible
        const int abase = (wave * 16 + l16) * AP + quad * 8;
        #pragma unroll
        for (int ks = 0; ks < 2; ++ks) {
            short8 af = *(const short8*)(lds_a + abase + ks * 32);
            #pragma unroll
            for (int t = 0; t < 4; ++t) {
                short8 bf = *(const short8*)(lds_w + (t * 16 + l16) * AP + ks * 32 + quad * 8);
                acc[t] = __builtin_amdgcn_mfma_f32_16x16x32_bf16(af, bf, acc[t], 0, 0, 0);
            }
        }
    }

    // write C: row = p0 + wave*16 + quad*4 + r, col = t*16 + l16
    const int row_base = p0 + wave * 16 + quad * 4;
    #pragma unroll
    for (int t = 0; t < 4; ++t) {
        #pragma unroll
        for (int r = 0; r < 4; ++r) {
            Y[(size_t)(row_base + r) * 64 + t * 16 + l16] = acc[t][r];
        }
    }

    // fused BN stats: per-lane over 4 rows -> shuffle across quads -> LDS -> 1 atomic/block
    __syncthreads();  // done reading lds_w; reuse as fp32 scratch
    float* red = (float*)lds_w;
    if (tid < 128) red[tid] = 0.0f;
    __syncthreads();
    #pragma unroll
    for (int t = 0; t < 4; ++t) {
        float s = acc[t][0] + acc[t][1] + acc[t][2] + acc[t][3];
        float ss = acc[t][0] * acc[t][0] + acc[t][1] * acc[t][1] +
                   acc[t][2] * acc[t][2] + acc[t][3] * acc[t][3];
        s += __shfl_down(s, 32);
        s += __shfl_down(s, 16);
        ss += __shfl_down(ss, 32);
        ss += __shfl_down(ss, 16);
        if (lane < 16) {
            atomicAdd(&red[t * 16 + l16], s);
            atomicAdd(&red[64 + t * 16 + l16], ss);
        }
    }
    __syncthreads();
    if (tid < 128) atomicAdd(&stats[tid], red[tid]);
}

// ---- bn + leakyrelu -> bf16 output (input to next conv) ----
__global__ void bnact_kernel(const float* __restrict__ Y, const float* __restrict__ stats,
                             const float* __restrict__ g, const float* __restrict__ b,
                             unsigned short* __restrict__ Xb, float slope) {
    __shared__ float scale[64], shift[64];
    int tid = threadIdx.x;
    if (tid < 64) {
        float m = stats[tid] * (1.0f / N_PTS);
        float v = stats[64 + tid] * (1.0f / N_PTS) - m * m;
        float rs = rsqrtf(v + 1e-4f);
        float sc = rs * g[tid];
        scale[tid] = sc;
        shift[tid] = b[tid] - m * sc;
    }
    __syncthreads();
    int i = blockIdx.x * blockDim.x + tid;
    const int total = N_PTS * 16;
    if (i >= total) return;
    int cb = (i & 15) << 2;
    float4 y = ((const float4*)Y)[i];
    float o0 = y.x * scale[cb] + shift[cb];
    float o1 = y.y * scale[cb + 1] + shift[cb + 1];
    float o2 = y.z * scale[cb + 2] + shift[cb + 2];
    float o3 = y.w * scale[cb + 3] + shift[cb + 3];
    o0 = o0 >= 0.f ? o0 : slope * o0;
    o1 = o1 >= 0.f ? o1 : slope * o1;
    o2 = o2 >= 0.f ? o2 : slope * o2;
    o3 = o3 >= 0.f ? o3 : slope * o3;
    ushort4 o;
    o.x = f2bf(o0); o.y = f2bf(o1); o.z = f2bf(o2); o.w = f2bf(o3);
    ((ushort4*)Xb)[i] = o;
}

// ---- final: bn3 + residual + leakyrelu(0.333) -> fp32 d_out (in place over Y) ----
__global__ void bnact_final_kernel(float* __restrict__ Y, const float* __restrict__ stats,
                                   const float* __restrict__ g, const float* __restrict__ b,
                                   const unsigned short* __restrict__ res) {
    __shared__ float scale[64], shift[64];
    int tid = threadIdx.x;
    if (tid < 64) {
        float m = stats[tid] * (1.0f / N_PTS);
        float v = stats[64 + tid] * (1.0f / N_PTS) - m * m;
        float rs = rsqrtf(v + 1e-4f);
        float sc = rs * g[tid];
        scale[tid] = sc;
        shift[tid] = b[tid] - m * sc;
    }
    __syncthreads();
    int i = blockIdx.x * blockDim.x + tid;
    const int total = N_PTS * 16;
    if (i >= total) return;
    int cb = (i & 15) << 2;
    float4 y = ((const float4*)Y)[i];
    ushort4 r4 = ((const ushort4*)res)[i];
    float o0 = y.x * scale[cb] + shift[cb] + bf2f(r4.x);
    float o1 = y.y * scale[cb + 1] + shift[cb + 1] + bf2f(r4.y);
    float o2 = y.z * scale[cb + 2] + shift[cb + 2] + bf2f(r4.z);
    float o3 = y.w * scale[cb + 3] + shift[cb + 3] + bf2f(r4.w);
    o0 = o0 >= 0.f ? o0 : 0.333f * o0;
    o1 = o1 >= 0.f ? o1 : 0.333f * o1;
    o2 = o2 >= 0.f ? o2 : 0.333f * o2;
    o3 = o3 >= 0.f ? o3 : 0.333f * o3;
    float4 o; o.x = o0; o.y = o1; o.z = o2; o.w = o3;
    ((float4*)Y)[i] = o;
}

extern "C" void kernel_launch(void* const* d_in, const int* in_sizes, int n_in,
                              void* d_out, int out_size, void* d_ws, size_t ws_size,
                              hipStream_t stream) {
    const float* feat = (const float*)d_in[0];
    const int* nbr = (const int*)d_in[1];
    const float* W1 = (const float*)d_in[2];
    const float* g1 = (const float*)d_in[3];
    const float* b1 = (const float*)d_in[4];
    const float* W2 = (const float*)d_in[5];
    const float* g2 = (const float*)d_in[6];
    const float* b2 = (const float*)d_in[7];
    const float* W3 = (const float*)d_in[8];
    const float* g3 = (const float*)d_in[9];
    const float* b3 = (const float*)d_in[10];
    float* Y = (float*)d_out;

    char* ws = (char*)d_ws;
    const size_t BF_BYTES = (size_t)N_PTS * 64 * 2;  // 51.2 MB
    unsigned short* B0 = (unsigned short*)ws;
    unsigned short* B1 = (unsigned short*)(ws + BF_BYTES);
    unsigned short* Wt = (unsigned short*)(ws + 2 * BF_BYTES);
    float* stats = (float*)(ws + 2 * BF_BYTES + (size_t)3 * KOFF * 4096 * 2);

    const int WSTRIDE = KOFF * 4096;  // 110592

    cast_feat_kernel<<<25000, 256, 0, stream>>>(feat, B0, N_PTS * 16);
    prep_w_all_kernel<<<(KOFF * 4096 + 255) / 256, 256, 0, stream>>>(W1, W2, W3, Wt, stats);

    // block 1
    conv_kernel<<<N_PTS / 128, 512, 0, stream>>>(B0, nbr, Wt, Y, stats);
    bnact_kernel<<<25000, 256, 0, stream>>>(Y, stats, g1, b1, B1, 0.05f);
    // block 2
    conv_kernel<<<N_PTS / 128, 512, 0, stream>>>(B1, nbr, Wt + WSTRIDE, Y, stats + 128);
    bnact_kernel<<<25000, 256, 0, stream>>>(Y, stats + 128, g2, b2, B0, 0.05f);
    // block 3 + residual
    conv_kernel<<<N_PTS / 128, 512, 0, stream>>>(B0, nbr, Wt + 2 * WSTRIDE, Y, stats + 256);
    bnact_final_kernel<<<25000, 256, 0, stream>>>(Y, stats + 256, g3, b3, B1);
}

// Round 5
// 1016.456 us; speedup vs baseline: 1.9222x; 1.0004x over previous
//
#include <hip/hip_runtime.h>
#include <hip/hip_bf16.h>

#define N_PTS 400000
#define KOFF 27
#define AP 72  // LDS row pitch in ushorts: 144B, breaks pow2 bank aliasing

typedef __attribute__((ext_vector_type(8))) short short8;
typedef __attribute__((ext_vector_type(4))) float float4v;

__device__ __forceinline__ unsigned short f2bf(float f) {
    union { float f; unsigned int u; } a; a.f = f;
    unsigned int u = a.u;
    unsigned int r = (u + 0x7FFFu + ((u >> 16) & 1u)) >> 16;
    return (unsigned short)r;
}

__device__ __forceinline__ float bf2f(unsigned short u) {
    union { unsigned int u; float f; } a; a.u = ((unsigned int)u) << 16;
    return a.f;
}

// ---- merged one-shot prep: cast features fp32->bf16 (blocks 0..24999),
// transpose+cast all 3 weight sets + zero stats (blocks 25000..25431) ----
__global__ void prep_kernel(const float* __restrict__ feat,
                            unsigned short* __restrict__ B0,
                            const float* __restrict__ W1,
                            const float* __restrict__ W2,
                            const float* __restrict__ W3,
                            unsigned short* __restrict__ Wt,
                            float* __restrict__ stats) {
    int b = blockIdx.x;
    int tid = threadIdx.x;
    if (b < 25000) {
        int i = b * 256 + tid;      // 6.4M float4 groups
        const float4* s4 = (const float4*)feat;
        float4 v = s4[i];
        ushort4 o;
        o.x = f2bf(v.x); o.y = f2bf(v.y); o.z = f2bf(v.z); o.w = f2bf(v.w);
        ((ushort4*)B0)[i] = o;
    } else {
        int i = (b - 25000) * 256 + tid;
        if (i < 384) stats[i] = 0.0f;
        if (i >= KOFF * 64 * 64) return;
        int k = i >> 12;
        int co = (i >> 6) & 63;
        int ci = i & 63;
        int src = (k << 12) + (ci << 6) + co;
        const int WS = KOFF * 4096;
        Wt[i] = f2bf(W1[src]);
        Wt[i + WS] = f2bf(W2[src]);
        Wt[i + 2 * WS] = f2bf(W3[src]);
    }
}

// ---- gather-GEMM + fused BN-stats reduction ----
// X: [N][64] bf16, nbr: [N][27] int, Wt: [27][64(co)][64(ci)] bf16
// Yout: [N][64] bf16 (OUTBF=1) or fp32 (OUTBF=0); stats: [128] fp32 pre-zeroed
// Block: 512 threads (8 waves), M-tile = 128 points; register prefetch dbuf.
// launch_bounds(512, 8): 4 blocks/CU. Y stores are NON-TEMPORAL (streaming,
// never re-read by this kernel) so they don't evict gather rows from L2.
template<int OUTBF>
__global__ __launch_bounds__(512, 8)
void conv_kernel(const unsigned short* __restrict__ X,
                 const int* __restrict__ nbr,
                 const unsigned short* __restrict__ Wt,
                 void* __restrict__ Yout,
                 float* __restrict__ stats) {
    __shared__ unsigned short lds_a[128 * AP];  // 18432 B
    __shared__ unsigned short lds_w[64 * AP];   //  9216 B
    const int tid = threadIdx.x;
    const int wave = tid >> 6;
    const int lane = tid & 63;
    const int quad = lane >> 4;
    const int l16 = lane & 15;
    const int p0 = blockIdx.x * 128;

    const int sr = tid >> 2;   // staging row 0..127 (4 threads/row)
    const int sq = tid & 3;    // 32B quarter of the 128B row
    const int wr = tid >> 3;   // W staging row (512 thr x 16B covers 8KB)
    const int wc = (tid & 7) << 3;

    float4v acc[4];
    #pragma unroll
    for (int t = 0; t < 4; ++t) acc[t] = (float4v){0.f, 0.f, 0.f, 0.f};

    // prefetch pipeline: indices 2 ahead, rows/weights 1 ahead
    const long nb = (long)(p0 + sr) * KOFF;
    int gi = nbr[nb];
    int gin = nbr[nb + 1];
    uint4 a0, a1, w0;
    {
        const uint4* srcA = (const uint4*)(X + ((size_t)gi << 6)) + sq * 2;
        a0 = srcA[0];
        a1 = srcA[1];
        w0 = ((const uint4*)Wt)[tid];
    }

    for (int k = 0; k < KOFF; ++k) {
        __syncthreads();  // previous iteration's compute done reading LDS
        *(uint4*)(lds_a + sr * AP + sq * 16) = a0;
        *(uint4*)(lds_a + sr * AP + sq * 16 + 8) = a1;
        *(uint4*)(lds_w + wr * AP + wc) = w0;
        if (k < KOFF - 1) {
            const uint4* srcA = (const uint4*)(X + ((size_t)gin << 6)) + sq * 2;
            a0 = srcA[0];
            a1 = srcA[1];
            w0 = ((const uint4*)(Wt + (((size_t)(k + 1)) << 12)))[tid];
            gin = (k < KOFF - 2) ? nbr[nb + k + 2] : 0;
        }
        __syncthreads();  // staged data visible
        const int abase = (wave * 16 + l16) * AP + quad * 8;
        #pragma unroll
        for (int ks = 0; ks < 2; ++ks) {
            short8 af = *(const short8*)(lds_a + abase + ks * 32);
            #pragma unroll
            for (int t = 0; t < 4; ++t) {
                short8 bf = *(const short8*)(lds_w + (t * 16 + l16) * AP + ks * 32 + quad * 8);
                acc[t] = __builtin_amdgcn_mfma_f32_16x16x32_bf16(af, bf, acc[t], 0, 0, 0);
            }
        }
    }

    // write C: row = p0 + wave*16 + quad*4 + r, col = t*16 + l16
    // non-temporal: streaming output, don't pollute L2 (gathers need it)
    const int row_base = p0 + wave * 16 + quad * 4;
    #pragma unroll
    for (int t = 0; t < 4; ++t) {
        #pragma unroll
        for (int r = 0; r < 4; ++r) {
            size_t idx = (size_t)(row_base + r) * 64 + t * 16 + l16;
            if (OUTBF) {
                __builtin_nontemporal_store(f2bf(acc[t][r]),
                                            (unsigned short*)Yout + idx);
            } else {
                __builtin_nontemporal_store(acc[t][r], (float*)Yout + idx);
            }
        }
    }

    // fused BN stats: per-lane over 4 rows -> shuffle across quads -> LDS -> 1 atomic/block
    __syncthreads();  // done reading lds_w; reuse as fp32 scratch
    float* red = (float*)lds_w;
    if (tid < 128) red[tid] = 0.0f;
    __syncthreads();
    #pragma unroll
    for (int t = 0; t < 4; ++t) {
        float s = acc[t][0] + acc[t][1] + acc[t][2] + acc[t][3];
        float ss = acc[t][0] * acc[t][0] + acc[t][1] * acc[t][1] +
                   acc[t][2] * acc[t][2] + acc[t][3] * acc[t][3];
        s += __shfl_down(s, 32);
        s += __shfl_down(s, 16);
        ss += __shfl_down(ss, 32);
        ss += __shfl_down(ss, 16);
        if (lane < 16) {
            atomicAdd(&red[t * 16 + l16], s);
            atomicAdd(&red[64 + t * 16 + l16], ss);
        }
    }
    __syncthreads();
    if (tid < 128) atomicAdd(&stats[tid], red[tid]);
}

// ---- bn + leakyrelu on bf16 Y -> bf16 output (input to next conv) ----
__global__ void bnact_kernel(const unsigned short* __restrict__ Yb,
                             const float* __restrict__ stats,
                             const float* __restrict__ g, const float* __restrict__ b,
                             unsigned short* __restrict__ Xb, float slope) {
    __shared__ float scale[64], shift[64];
    int tid = threadIdx.x;
    if (tid < 64) {
        float m = stats[tid] * (1.0f / N_PTS);
        float v = stats[64 + tid] * (1.0f / N_PTS) - m * m;
        float rs = rsqrtf(v + 1e-4f);
        float sc = rs * g[tid];
        scale[tid] = sc;
        shift[tid] = b[tid] - m * sc;
    }
    __syncthreads();
    int i = blockIdx.x * blockDim.x + tid;
    const int total = N_PTS * 16;
    if (i >= total) return;
    int cb = (i & 15) << 2;
    ushort4 y4 = ((const ushort4*)Yb)[i];
    float o0 = bf2f(y4.x) * scale[cb] + shift[cb];
    float o1 = bf2f(y4.y) * scale[cb + 1] + shift[cb + 1];
    float o2 = bf2f(y4.z) * scale[cb + 2] + shift[cb + 2];
    float o3 = bf2f(y4.w) * scale[cb + 3] + shift[cb + 3];
    o0 = o0 >= 0.f ? o0 : slope * o0;
    o1 = o1 >= 0.f ? o1 : slope * o1;
    o2 = o2 >= 0.f ? o2 : slope * o2;
    o3 = o3 >= 0.f ? o3 : slope * o3;
    ushort4 o;
    o.x = f2bf(o0); o.y = f2bf(o1); o.z = f2bf(o2); o.w = f2bf(o3);
    ((ushort4*)Xb)[i] = o;
}

// ---- final: bn3 + residual + leakyrelu(0.333) -> fp32 d_out (in place over Y) ----
__global__ void bnact_final_kernel(float* __restrict__ Y, const float* __restrict__ stats,
                                   const float* __restrict__ g, const float* __restrict__ b,
                                   const unsigned short* __restrict__ res) {
    __shared__ float scale[64], shift[64];
    int tid = threadIdx.x;
    if (tid < 64) {
        float m = stats[tid] * (1.0f / N_PTS);
        float v = stats[64 + tid] * (1.0f / N_PTS) - m * m;
        float rs = rsqrtf(v + 1e-4f);
        float sc = rs * g[tid];
        scale[tid] = sc;
        shift[tid] = b[tid] - m * sc;
    }
    __syncthreads();
    int i = blockIdx.x * blockDim.x + tid;
    const int total = N_PTS * 16;
    if (i >= total) return;
    int cb = (i & 15) << 2;
    float4 y = ((const float4*)Y)[i];
    ushort4 r4 = ((const ushort4*)res)[i];
    float o0 = y.x * scale[cb] + shift[cb] + bf2f(r4.x);
    float o1 = y.y * scale[cb + 1] + shift[cb + 1] + bf2f(r4.y);
    float o2 = y.z * scale[cb + 2] + shift[cb + 2] + bf2f(r4.z);
    float o3 = y.w * scale[cb + 3] + shift[cb + 3] + bf2f(r4.w);
    o0 = o0 >= 0.f ? o0 : 0.333f * o0;
    o1 = o1 >= 0.f ? o1 : 0.333f * o1;
    o2 = o2 >= 0.f ? o2 : 0.333f * o2;
    o3 = o3 >= 0.f ? o3 : 0.333f * o3;
    float4 o; o.x = o0; o.y = o1; o.z = o2; o.w = o3;
    ((float4*)Y)[i] = o;
}

extern "C" void kernel_launch(void* const* d_in, const int* in_sizes, int n_in,
                              void* d_out, int out_size, void* d_ws, size_t ws_size,
                              hipStream_t stream) {
    const float* feat = (const float*)d_in[0];
    const int* nbr = (const int*)d_in[1];
    const float* W1 = (const float*)d_in[2];
    const float* g1 = (const float*)d_in[3];
    const float* b1 = (const float*)d_in[4];
    const float* W2 = (const float*)d_in[5];
    const float* g2 = (const float*)d_in[6];
    const float* b2 = (const float*)d_in[7];
    const float* W3 = (const float*)d_in[8];
    const float* g3 = (const float*)d_in[9];
    const float* b3 = (const float*)d_in[10];
    float* Y = (float*)d_out;
    // bf16 Y for conv1/conv2 lives in d_out's lower half (fp32 Y unused
    // until conv3, which then overwrites the whole buffer in place).
    unsigned short* Ybf = (unsigned short*)d_out;

    char* ws = (char*)d_ws;
    const size_t BF_BYTES = (size_t)N_PTS * 64 * 2;  // 51.2 MB
    unsigned short* B0 = (unsigned short*)ws;
    unsigned short* B1 = (unsigned short*)(ws + BF_BYTES);
    unsigned short* Wt = (unsigned short*)(ws + 2 * BF_BYTES);
    float* stats = (float*)(ws + 2 * BF_BYTES + (size_t)3 * KOFF * 4096 * 2);

    const int WSTRIDE = KOFF * 4096;  // 110592

    // merged cast + weight-prep (one launch)
    prep_kernel<<<25432, 256, 0, stream>>>(feat, B0, W1, W2, W3, Wt, stats);

    // block 1 (bf16 Y)
    conv_kernel<1><<<N_PTS / 128, 512, 0, stream>>>(B0, nbr, Wt, (void*)Ybf, stats);
    bnact_kernel<<<25000, 256, 0, stream>>>(Ybf, stats, g1, b1, B1, 0.05f);
    // block 2 (bf16 Y)
    conv_kernel<1><<<N_PTS / 128, 512, 0, stream>>>(B1, nbr, Wt + WSTRIDE, (void*)Ybf, stats + 128);
    bnact_kernel<<<25000, 256, 0, stream>>>(Ybf, stats + 128, g2, b2, B0, 0.05f);
    // block 3 (fp32 Y in d_out) + residual
    conv_kernel<0><<<N_PTS / 128, 512, 0, stream>>>(B0, nbr, Wt + 2 * WSTRIDE, (void*)Y, stats + 256);
    bnact_final_kernel<<<25000, 256, 0, stream>>>(Y, stats + 256, g3, b3, B1);
}